// Round 3
// baseline (5075.468 us; speedup 1.0000x reference)
//
#include <hip/hip_runtime.h>
#include <math.h>
#include <float.h>

#define NN 100000
#define NE 1600000

#define SCAN_T 256
#define SCAN_E 1024
#define SCAN_NB ((NN + SCAN_E - 1) / SCAN_E)   // 98

// ---------------- tiled fused linear: [q|k|v|skip] = x @ [Wq|Wk|Wv|Ws] + b ----------------
// block: 256 threads = 32 col-groups (8 cols each) x 8 node-groups (8 nodes each)
// covers 64 nodes x 256 cols per chunk; x tile staged in LDS (broadcast reads)
template<int IN, int OUT>
__global__ __launch_bounds__(256, 2)
void linear_qkvs(const float* __restrict__ x,
                 const float* __restrict__ Wq, const float* __restrict__ bq,
                 const float* __restrict__ Wk, const float* __restrict__ bk,
                 const float* __restrict__ Wv, const float* __restrict__ bv,
                 const float* __restrict__ Ws, const float* __restrict__ bs,
                 float* __restrict__ q, float* __restrict__ k,
                 float* __restrict__ v, float* __restrict__ outskip) {
    constexpr int NC = 4 * OUT;
    constexpr int NCHUNK = (NC + 255) / 256;
    constexpr int S4 = (IN + 4) / 4;          // LDS row stride in float4
    __shared__ float4 xs4[64 * S4];

    const int t = threadIdx.x;
    const int cg = t & 31;                    // col group: 8 cols
    const int ng = t >> 5;                    // node group: 8 nodes (stride-8 interleaved)
    const int nbase = blockIdx.x * 64;

    // ---- stage x tile (64 x IN) ----
    constexpr int NF4 = 64 * IN / 4;
    const float4* xg = (const float4*)x;
    for (int idx = t; idx < NF4; idx += 256) {
        int row = idx / (IN / 4);
        int c4  = idx % (IN / 4);
        int n_g = nbase + row;
        float4 val = (n_g < NN) ? xg[(size_t)n_g * (IN / 4) + c4]
                                : make_float4(0.f, 0.f, 0.f, 0.f);
        xs4[row * S4 + c4] = val;
    }
    __syncthreads();

    for (int chunk = 0; chunk < NCHUNK; ++chunk) {
        int c0 = chunk * 256 + cg * 8;
        if (c0 >= NC) continue;
        int mat = c0 / OUT;
        int ch  = c0 - mat * OUT;             // ch % 8 == 0 (OUT % 8 == 0)
        const float* W = (mat == 0) ? Wq : (mat == 1) ? Wk : (mat == 2) ? Wv : Ws;
        const float* B = (mat == 0) ? bq : (mat == 1) ? bk : (mat == 2) ? bv : bs;
        float*       O = (mat == 0) ? q  : (mat == 1) ? k  : (mat == 2) ? v  : outskip;

        float4 b0 = *(const float4*)(B + ch);
        float4 b1 = *(const float4*)(B + ch + 4);
        float4 acc0[8], acc1[8];
#pragma unroll
        for (int i = 0; i < 8; ++i) { acc0[i] = b0; acc1[i] = b1; }

#pragma unroll
        for (int g = 0; g < IN / 4; ++g) {
            float4 xa[8];
#pragma unroll
            for (int i = 0; i < 8; ++i)
                xa[i] = xs4[(i * 8 + ng) * S4 + g];   // 2 distinct addrs/wave -> broadcast
#pragma unroll
            for (int kk = 0; kk < 4; ++kk) {
                int krow = g * 4 + kk;
                float4 w0 = *(const float4*)(W + (size_t)krow * OUT + ch);
                float4 w1 = *(const float4*)(W + (size_t)krow * OUT + ch + 4);
#pragma unroll
                for (int i = 0; i < 8; ++i) {
                    float xv = (kk == 0) ? xa[i].x : (kk == 1) ? xa[i].y
                             : (kk == 2) ? xa[i].z : xa[i].w;
                    acc0[i].x += xv * w0.x; acc0[i].y += xv * w0.y;
                    acc0[i].z += xv * w0.z; acc0[i].w += xv * w0.w;
                    acc1[i].x += xv * w1.x; acc1[i].y += xv * w1.y;
                    acc1[i].z += xv * w1.z; acc1[i].w += xv * w1.w;
                }
            }
        }
#pragma unroll
        for (int i = 0; i < 8; ++i) {
            int n_g = nbase + i * 8 + ng;
            if (n_g < NN) {
                float4* dst = (float4*)(O + (size_t)n_g * OUT + ch);
                dst[0] = acc0[i];
                dst[1] = acc1[i];
            }
        }
    }
}

// ---------------- CSR build (once; topology shared by all layers) ----------------
__global__ __launch_bounds__(256)
void hist_k(const int* __restrict__ ei, int* __restrict__ counts) {
    int e = blockIdx.x * blockDim.x + threadIdx.x;
    if (e < NE) atomicAdd(&counts[ei[NE + e]], 1);
}

__global__ __launch_bounds__(SCAN_T)
void scan1(const int* __restrict__ counts, int* __restrict__ offsets,
           int* __restrict__ blocksums) {
    __shared__ int lds[SCAN_T];
    int t = threadIdx.x;
    int base = blockIdx.x * SCAN_E + t * 4;
    int vals[4];
    int s = 0;
#pragma unroll
    for (int j = 0; j < 4; ++j) {
        int idx = base + j;
        vals[j] = (idx < NN) ? counts[idx] : 0;
        s += vals[j];
    }
    lds[t] = s;
    __syncthreads();
    for (int off = 1; off < SCAN_T; off <<= 1) {
        int xx = (t >= off) ? lds[t - off] : 0;
        __syncthreads();
        lds[t] += xx;
        __syncthreads();
    }
    int run = (t > 0) ? lds[t - 1] : 0;
    if (t == SCAN_T - 1) blocksums[blockIdx.x] = lds[t];
#pragma unroll
    for (int j = 0; j < 4; ++j) {
        int idx = base + j;
        if (idx < NN) offsets[idx] = run;
        run += vals[j];
    }
}

__global__ __launch_bounds__(128)
void scan2(int* __restrict__ blocksums) {
    __shared__ int lds[128];
    int t = threadIdx.x;
    lds[t] = (t < SCAN_NB) ? blocksums[t] : 0;
    __syncthreads();
    for (int off = 1; off < 128; off <<= 1) {
        int xx = (t >= off) ? lds[t - off] : 0;
        __syncthreads();
        lds[t] += xx;
        __syncthreads();
    }
    if (t < SCAN_NB) blocksums[t] = (t > 0) ? lds[t - 1] : 0;
}

__global__ __launch_bounds__(256)
void scan3(int* __restrict__ offsets, int* __restrict__ pos,
           const int* __restrict__ blocksums) {
    int i = blockIdx.x * blockDim.x + threadIdx.x;
    if (i < NN) {
        int o = offsets[i] + blocksums[i / SCAN_E];
        offsets[i] = o;
        pos[i] = o;
    }
    if (i == 0) offsets[NN] = NE;
}

__global__ __launch_bounds__(256)
void build_csr(const int* __restrict__ ei, int* __restrict__ pos,
               int* __restrict__ sorted_src) {
    int e = blockIdx.x * blockDim.x + threadIdx.x;
    if (e < NE) {
        int d = ei[NE + e];
        int p = atomicAdd(&pos[d], 1);
        sorted_src[p] = ei[e];
    }
}

// ---- 16-lane row sum via DPP rotates (VALU pipe, no LDS) ----
__device__ __forceinline__ float row16_sum(float x) {
    int y;
    y = __builtin_amdgcn_update_dpp(0, __float_as_int(x), 0x121, 0xF, 0xF, true); x += __int_as_float(y); // ror:1
    y = __builtin_amdgcn_update_dpp(0, __float_as_int(x), 0x122, 0xF, 0xF, true); x += __int_as_float(y); // ror:2
    y = __builtin_amdgcn_update_dpp(0, __float_as_int(x), 0x124, 0xF, 0xF, true); x += __int_as_float(y); // ror:4
    y = __builtin_amdgcn_update_dpp(0, __float_as_int(x), 0x128, 0xF, 0xF, true); x += __int_as_float(y); // ror:8
    return x;
}

// ---------------- fused attention gather: one wave per node ----------------
// 4 independent edge-groups of 16 lanes each; each group runs its own online
// softmax over edges beg+g, beg+g+4, ...; groups merged once at the end.
template<int C, bool RELU>
__global__ __launch_bounds__(256)
void attn_gather(const int* __restrict__ offsets,
                 const int* __restrict__ sorted_src,
                 const float* __restrict__ q, const float* __restrict__ kmat,
                 const float* __restrict__ v,
                 float* __restrict__ out, float scale) {
    const int wid  = (int)((blockIdx.x * blockDim.x + threadIdx.x) >> 6);
    const int lane = threadIdx.x & 63;
    if (wid >= NN) return;
    const int grp = lane >> 4;
    const int ch  = (lane & 15) * 4;
    constexpr bool P2 = (C > 64);
    const bool hi = P2 && (ch + 64 < C);

    const int beg = offsets[wid], end = offsets[wid + 1];

    float4 qv0 = *(const float4*)(q + (size_t)wid * C + ch);
    float4 qv1 = make_float4(0.f, 0.f, 0.f, 0.f);
    if (hi) qv1 = *(const float4*)(q + (size_t)wid * C + ch + 64);

    float m = -FLT_MAX, l = 0.f;
    float4 a0 = make_float4(0.f, 0.f, 0.f, 0.f);
    float4 a1 = make_float4(0.f, 0.f, 0.f, 0.f);

    for (int i = beg + grp; i < end; i += 4) {
        int src = sorted_src[i];
        const float* kr = kmat + (size_t)src * C;
        const float* vr = v    + (size_t)src * C;
        float4 kv0 = *(const float4*)(kr + ch);
        float4 vv0 = *(const float4*)(vr + ch);
        float4 kv1 = make_float4(0.f, 0.f, 0.f, 0.f);
        float4 vv1 = make_float4(0.f, 0.f, 0.f, 0.f);
        if (hi) {
            kv1 = *(const float4*)(kr + ch + 64);
            vv1 = *(const float4*)(vr + ch + 64);
        }
        float part = qv0.x * kv0.x + qv0.y * kv0.y + qv0.z * kv0.z + qv0.w * kv0.w;
        if (P2) part += qv1.x * kv1.x + qv1.y * kv1.y + qv1.z * kv1.z + qv1.w * kv1.w;
        float s = row16_sum(part) * scale;
        float mn = fmaxf(m, s);
        float al = __expf(m - mn);   // first edge: exp(-huge) -> 0
        float w  = __expf(s - mn);
        l = l * al + w;
        a0.x = a0.x * al + w * vv0.x; a0.y = a0.y * al + w * vv0.y;
        a0.z = a0.z * al + w * vv0.z; a0.w = a0.w * al + w * vv0.w;
        if (P2) {
            a1.x = a1.x * al + w * vv1.x; a1.y = a1.y * al + w * vv1.y;
            a1.z = a1.z * al + w * vv1.z; a1.w = a1.w * al + w * vv1.w;
        }
        m = mn;
    }

    // merge the 4 groups: butterfly over lane-xor 16, 32
#pragma unroll
    for (int d = 16; d <= 32; d <<= 1) {
        float mo = __shfl_xor(m, d);
        float lo = __shfl_xor(l, d);
        float4 ao0, ao1;
        ao0.x = __shfl_xor(a0.x, d); ao0.y = __shfl_xor(a0.y, d);
        ao0.z = __shfl_xor(a0.z, d); ao0.w = __shfl_xor(a0.w, d);
        if (P2) {
            ao1.x = __shfl_xor(a1.x, d); ao1.y = __shfl_xor(a1.y, d);
            ao1.z = __shfl_xor(a1.z, d); ao1.w = __shfl_xor(a1.w, d);
        }
        float mn = fmaxf(m, mo);
        float e1 = (l  > 0.f) ? __expf(m  - mn) : 0.f;
        float e2 = (lo > 0.f) ? __expf(mo - mn) : 0.f;
        l = l * e1 + lo * e2;
        a0.x = a0.x * e1 + ao0.x * e2; a0.y = a0.y * e1 + ao0.y * e2;
        a0.z = a0.z * e1 + ao0.z * e2; a0.w = a0.w * e1 + ao0.w * e2;
        if (P2) {
            a1.x = a1.x * e1 + ao1.x * e2; a1.y = a1.y * e1 + ao1.y * e2;
            a1.z = a1.z * e1 + ao1.z * e2; a1.w = a1.w * e1 + ao1.w * e2;
        }
        m = mn;
    }

    if (lane < 16) {
        float inv = (l > 0.f) ? 1.f / l : 0.f;
        size_t o = (size_t)wid * C + ch;
        float4 sk = *(const float4*)(out + o);
        float4 r;
        r.x = sk.x + a0.x * inv; r.y = sk.y + a0.y * inv;
        r.z = sk.z + a0.z * inv; r.w = sk.w + a0.w * inv;
        if (RELU) {
            r.x = fmaxf(r.x, 0.f); r.y = fmaxf(r.y, 0.f);
            r.z = fmaxf(r.z, 0.f); r.w = fmaxf(r.w, 0.f);
        }
        *(float4*)(out + o) = r;
        if (hi) {
            float4 sk1 = *(const float4*)(out + o + 64);
            float4 r1;
            r1.x = sk1.x + a1.x * inv; r1.y = sk1.y + a1.y * inv;
            r1.z = sk1.z + a1.z * inv; r1.w = sk1.w + a1.w * inv;
            if (RELU) {
                r1.x = fmaxf(r1.x, 0.f); r1.y = fmaxf(r1.y, 0.f);
                r1.z = fmaxf(r1.z, 0.f); r1.w = fmaxf(r1.w, 0.f);
            }
            *(float4*)(out + o + 64) = r1;
        }
    }
}

// ---------------- host side ----------------
template<int IN, int OUT, bool RELU>
static void run_layer(const float* xin, const float* const* Wb,
                      const int* offsets, const int* sorted_src,
                      float* q, float* k, float* v,
                      float* out, hipStream_t stream) {
    dim3 gl((NN + 63) / 64);
    linear_qkvs<IN, OUT><<<gl, 256, 0, stream>>>(
        xin, Wb[0], Wb[1], Wb[2], Wb[3], Wb[4], Wb[5], Wb[6], Wb[7],
        q, k, v, out);

    float scale = 1.0f / sqrtf((float)OUT);
    attn_gather<OUT, RELU><<<(NN + 3) / 4, 256, 0, stream>>>(
        offsets, sorted_src, q, k, v, out, scale);
}

extern "C" void kernel_launch(void* const* d_in, const int* in_sizes, int n_in,
                              void* d_out, int out_size, void* d_ws, size_t ws_size,
                              hipStream_t stream) {
    const float* x  = (const float*)d_in[0];
    const int*   ei = (const int*)d_in[1];
    const float* Wb0[8], *Wb1[8], *Wb2[8];
    for (int i = 0; i < 8; ++i) {
        Wb0[i] = (const float*)d_in[2 + i];
        Wb1[i] = (const float*)d_in[10 + i];
        Wb2[i] = (const float*)d_in[18 + i];
    }
    float* out = (float*)d_out;

    char* ws = (char*)d_ws;
    const size_t CMAX = 112;
    size_t off = 0;
    float* q          = (float*)(ws + off); off += (size_t)NN * CMAX * 4;
    float* k          = (float*)(ws + off); off += (size_t)NN * CMAX * 4;
    float* v          = (float*)(ws + off); off += (size_t)NN * CMAX * 4;
    float* h0         = (float*)(ws + off); off += (size_t)NN * 64 * 4;
    float* h1         = (float*)(ws + off); off += (size_t)NN * 64 * 4;
    int*   sorted_src = (int*)(ws + off);   off += (size_t)NE * 4;
    int*   counts     = (int*)(ws + off);   off += (size_t)NN * 4;
    int*   offsets    = (int*)(ws + off);   off += (size_t)(NN + 1) * 4;
    int*   pos        = (int*)(ws + off);   off += (size_t)NN * 4;
    int*   blocksums  = (int*)(ws + off);   off += (size_t)SCAN_NB * 4;
    (void)ws_size; (void)in_sizes; (void)n_in; (void)out_size;

    // ---- build CSR (grouped by dst) once ----
    hipMemsetAsync(counts, 0, (size_t)NN * sizeof(int), stream);
    hist_k<<<(NE + 255) / 256, 256, 0, stream>>>(ei, counts);
    scan1<<<SCAN_NB, SCAN_T, 0, stream>>>(counts, offsets, blocksums);
    scan2<<<1, 128, 0, stream>>>(blocksums);
    scan3<<<(NN + 255) / 256, 256, 0, stream>>>(offsets, pos, blocksums);
    build_csr<<<(NE + 255) / 256, 256, 0, stream>>>(ei, pos, sorted_src);

    run_layer<8,  64, true >(x,  Wb0, offsets, sorted_src, q, k, v, h0,  stream);
    run_layer<64, 64, true >(h0, Wb1, offsets, sorted_src, q, k, v, h1,  stream);
    run_layer<64, 112, false>(h1, Wb2, offsets, sorted_src, q, k, v, out, stream);
}